// Round 2
// baseline (410.880 us; speedup 1.0000x reference)
//
#include <hip/hip_runtime.h>
#include <hip/hip_bf16.h>
#include <cstdint>
#include <cstddef>

#define SCALE_ 0.125f
// B=16 N=256 C=512 H=8 HD=64 E=64

__device__ __forceinline__ unsigned pk2(float a, float b) {
  union { __hip_bfloat16 h[2]; unsigned u; } x;
  x.h[0] = __float2bfloat16(a);
  x.h[1] = __float2bfloat16(b);
  return x.u;
}
__device__ __forceinline__ float blo(unsigned u) { return __uint_as_float(u << 16); }
__device__ __forceinline__ float bhi(unsigned u) { return __uint_as_float(u & 0xffff0000u); }

// ---------------- Kernel 1: QKV projection GEMM (f32 in, bf16 out) ----------
// X[4096][512] ; W[1536][512] (row-major, y = x @ W^T)
// qb : bf16  [BH][N][64]
// ktp: uint  [BH][32][256]  pairs along d: (d=2*d2, 2*d2+1) for key col y
// vp : uint  [BH][128][64]  pairs along y: (y=2*y2, 2*y2+1) for dim d
__global__ __launch_bounds__(256) void qkv_gemm(
    const float* __restrict__ X, const float* __restrict__ W,
    unsigned short* __restrict__ qb, unsigned* __restrict__ ktp, unsigned* __restrict__ vp)
{
  __shared__ alignas(16) float A_s[16][136];
  __shared__ alignas(16) float W_s[16][72];
  const int t  = threadIdx.x;
  const int m0 = blockIdx.x * 128;
  const int o0 = blockIdx.y * 64;
  const int tm = (t & 15) * 8;
  const int to = (t >> 4) * 4;
  float acc[8][4];
  #pragma unroll
  for (int i = 0; i < 8; i++)
    #pragma unroll
    for (int j = 0; j < 4; j++) acc[i][j] = 0.f;

  const float4* X4 = (const float4*)X;
  const float4* W4 = (const float4*)W;
  for (int c0 = 0; c0 < 512; c0 += 16) {
    #pragma unroll
    for (int i = 0; i < 2; i++) {
      int id = t + 256 * i;
      int row = id >> 2, quad = id & 3;
      float4 a = X4[(size_t)(m0 + row) * 128 + (c0 >> 2) + quad];
      A_s[quad*4+0][row] = a.x; A_s[quad*4+1][row] = a.y;
      A_s[quad*4+2][row] = a.z; A_s[quad*4+3][row] = a.w;
    }
    {
      int row = t >> 2, quad = t & 3;
      float4 w = W4[(size_t)(o0 + row) * 128 + (c0 >> 2) + quad];
      W_s[quad*4+0][row] = w.x; W_s[quad*4+1][row] = w.y;
      W_s[quad*4+2][row] = w.z; W_s[quad*4+3][row] = w.w;
    }
    __syncthreads();
    #pragma unroll
    for (int kk = 0; kk < 16; kk++) {
      float4 a0 = *(const float4*)&A_s[kk][tm];
      float4 a1 = *(const float4*)&A_s[kk][tm + 4];
      float4 w0 = *(const float4*)&W_s[kk][to];
      float am[8] = {a0.x,a0.y,a0.z,a0.w,a1.x,a1.y,a1.z,a1.w};
      float wn[4] = {w0.x,w0.y,w0.z,w0.w};
      #pragma unroll
      for (int i = 0; i < 8; i++)
        #pragma unroll
        for (int j = 0; j < 4; j++) acc[i][j] += am[i] * wn[j];
    }
    __syncthreads();
  }
  // scatter store (bf16): this block's o-range is one (three,h) group
  const int three = o0 >> 9;
  const int h = (o0 >> 6) & 7;
  if (three == 0) {
    #pragma unroll
    for (int i = 0; i < 8; i++) {
      int m = m0 + tm + i;
      int b = m >> 8, n = m & 255;
      unsigned u0 = pk2(acc[i][0], acc[i][1]);
      unsigned u1 = pk2(acc[i][2], acc[i][3]);
      *(uint2*)&qb[((size_t)(b*8 + h)*256 + n)*64 + to] = make_uint2(u0, u1);
    }
  } else if (three == 1) {
    #pragma unroll
    for (int i = 0; i < 8; i++) {
      int m = m0 + tm + i;
      int b = m >> 8, n = m & 255;
      ktp[(size_t)(b*8 + h)*8192 + ((to >> 1) + 0)*256 + n] = pk2(acc[i][0], acc[i][1]);
      ktp[(size_t)(b*8 + h)*8192 + ((to >> 1) + 1)*256 + n] = pk2(acc[i][2], acc[i][3]);
    }
  } else {
    #pragma unroll
    for (int i = 0; i < 8; i += 2) {  // pair rows n, n+1 (tm%8==0 so n even)
      int m = m0 + tm + i;
      int b = m >> 8, n = m & 255;
      int y2 = n >> 1;
      #pragma unroll
      for (int j = 0; j < 4; j++)
        vp[(size_t)(b*8 + h)*8192 + y2*64 + to + j] = pk2(acc[i][j], acc[i+1][j]);
    }
  }
}

// ---------------- Kernel 2: fused attn + edge pipeline ----------------------
// one block per (b, pair of query rows x0,x0+1); 256 threads = 4 waves
__global__ __launch_bounds__(256) void fused_attn(
    const unsigned short* __restrict__ qb, const unsigned* __restrict__ ktp,
    const unsigned* __restrict__ vp,
    const float* __restrict__ edge, const unsigned char* __restrict__ mask,
    const float* __restrict__ rw, const float* __restrict__ rb,
    const float* __restrict__ ew, const float* __restrict__ eb,
    const float* __restrict__ fcw, const float* __restrict__ fcb,
    float* __restrict__ out_edge, unsigned short* __restrict__ tmpb)
{
  __shared__ alignas(16) float q_s[2][8][64];
  __shared__ alignas(16) float rw_s[64][8];   // [e][h]
  __shared__ alignas(16) float ew_s[64][8];   // [e][h]
  __shared__ alignas(16) float s_s[2][8][256];   // raw attn (residual)
  __shared__ alignas(16) float p_s[2][8][256];   // unnormalized exp
  __shared__ alignas(16) float eo_s[8][256];
  __shared__ alignas(16) float mk[2][256];       // additive mask (0 or -1e30)
  __shared__ float pl2[2][64];
  __shared__ float inv_s[2][8];

  const int t = threadIdx.x;
  const int lane = t & 63;
  const int wv = t >> 6;
  const int bid = blockIdx.x;
  const int b = bid >> 7;
  const int x0 = (bid & 127) * 2;

  // ---- phase 1: stage q (bf16->f32), small weights, mask
  const __hip_bfloat16* qh = (const __hip_bfloat16*)qb;
  for (int i = t; i < 1024; i += 256) {
    int r = i >> 9, h = (i >> 6) & 7, d = i & 63;
    q_s[r][h][d] = __bfloat162float(qh[((size_t)(b*8 + h)*256 + x0 + r)*64 + d]);
  }
  for (int i = t; i < 512; i += 256) { int e = i >> 3, h = i & 7; rw_s[e][h] = rw[h*64 + e]; }
  for (int i = t; i < 512; i += 256) ((float*)ew_s)[i] = ew[i];
  for (int i = t; i < 512; i += 256) {
    int r = i >> 8, yy = i & 255;
    mk[r][yy] = mask[((size_t)b*256 + x0 + r)*256 + yy] ? -1e30f : 0.f;
  }
  __syncthreads();

  const int y = t;
  float acc0[8], acc1[8];
  #pragma unroll
  for (int h = 0; h < 8; h++) { float rv = rb[h]; acc0[h] = rv; acc1[h] = rv; }

  // ---- phase 2a: edge bias (the HBM stream: 268 MB read, coalesced over y)
  {
    const float* ep = edge + (size_t)b*64*65536 + x0*256 + y;
    const float4* rw4 = (const float4*)rw_s;
    #pragma unroll 4
    for (int e = 0; e < 64; e++) {
      float v0 = ep[(size_t)e*65536];
      float v1 = ep[(size_t)e*65536 + 256];
      float4 w0 = rw4[e*2], w1 = rw4[e*2+1];
      acc0[0] += v0*w0.x; acc0[1] += v0*w0.y; acc0[2] += v0*w0.z; acc0[3] += v0*w0.w;
      acc0[4] += v0*w1.x; acc0[5] += v0*w1.y; acc0[6] += v0*w1.z; acc0[7] += v0*w1.w;
      acc1[0] += v1*w0.x; acc1[1] += v1*w0.y; acc1[2] += v1*w0.z; acc1[3] += v1*w0.w;
      acc1[4] += v1*w1.x; acc1[5] += v1*w1.y; acc1[6] += v1*w1.z; acc1[7] += v1*w1.w;
    }
  }

  // ---- phase 2b: QK^T (ktp is [bh][d2][y] uint pairs: 4B/lane, coalesced over y)
  #pragma unroll
  for (int h = 0; h < 8; h++) {
    const unsigned* kp = ktp + (size_t)(b*8 + h)*8192 + y;
    float qk0 = 0.f, qk1 = 0.f;
    #pragma unroll 8
    for (int d2 = 0; d2 < 32; d2++) {
      unsigned u = kp[d2*256];
      float k0 = blo(u), k1 = bhi(u);
      float2 qa = *(const float2*)&q_s[0][h][2*d2];
      float2 qc = *(const float2*)&q_s[1][h][2*d2];
      qk0 += qa.x*k0 + qa.y*k1;
      qk1 += qc.x*k0 + qc.y*k1;
    }
    acc0[h] += SCALE_ * qk0;
    acc1[h] += SCALE_ * qk1;
  }
  #pragma unroll
  for (int h = 0; h < 8; h++) { s_s[0][h][y] = acc0[h]; s_s[1][h][y] = acc1[h]; }
  __syncthreads();

  // ---- phase 3: softmax, wave wv owns rows wv*4..wv*4+3 of the 16 (r,h) rows
  #pragma unroll
  for (int qq = 0; qq < 4; qq++) {
    int rr = wv*4 + qq;
    int r = rr >> 3, h = rr & 7;
    float4 sv = *(const float4*)&s_s[r][h][lane*4];
    float4 mv = *(const float4*)&mk[r][lane*4];
    float m0v = sv.x+mv.x, m1v = sv.y+mv.y, m2v = sv.z+mv.z, m3v = sv.w+mv.w;
    float mx = fmaxf(fmaxf(m0v, m1v), fmaxf(m2v, m3v));
    #pragma unroll
    for (int off = 32; off; off >>= 1) mx = fmaxf(mx, __shfl_xor(mx, off, 64));
    float e0 = __expf(m0v-mx), e1 = __expf(m1v-mx), e2 = __expf(m2v-mx), e3 = __expf(m3v-mx);
    *(float4*)&p_s[r][h][lane*4] = make_float4(e0, e1, e2, e3);
    float sm = e0 + e1 + e2 + e3;
    #pragma unroll
    for (int off = 32; off; off >>= 1) sm += __shfl_xor(sm, off, 64);
    if (lane == 0) inv_s[r][h] = 1.0f / sm;
  }
  __syncthreads();

  // ---- phase 4: PV. wave wv does heads wv and wv+4; vp pairs along y (4B/lane)
  float nacc[2][2]; // [pass][r]
  #pragma unroll
  for (int pass = 0; pass < 2; pass++) {
    int h = wv + pass*4;
    const unsigned* vpp = vp + (size_t)(b*8 + h)*8192 + lane;
    const float4* pa = (const float4*)p_s[0][h];
    const float4* pb = (const float4*)p_s[1][h];
    float a0 = 0.f, a1 = 0.f;
    #pragma unroll 4
    for (int y4 = 0; y4 < 64; y4++) {
      float4 P0 = pa[y4], P1 = pb[y4];
      unsigned ua = vpp[(y4*2+0)*64];
      unsigned ub = vpp[(y4*2+1)*64];
      float v0 = blo(ua), v1 = bhi(ua), v2 = blo(ub), v3 = bhi(ub);
      a0 += P0.x*v0 + P0.y*v1 + P0.z*v2 + P0.w*v3;
      a1 += P1.x*v0 + P1.y*v1 + P1.z*v2 + P1.w*v3;
    }
    nacc[pass][0] = a0 * inv_s[0][wv + pass*4];
    nacc[pass][1] = a1 * inv_s[1][wv + pass*4];
  }

  // ---- phase 5: expand + edge_out write + row pooling (chunks of 8 e)
  const float4* ew4 = (const float4*)ew_s;
  for (int r = 0; r < 2; r++) {
    float t8v[8];
    #pragma unroll
    for (int h = 0; h < 8; h++)
      t8v[h] = p_s[r][h][y] * inv_s[r][h] + s_s[r][h][y];  // attn_sm + residual
    for (int c8 = 0; c8 < 8; c8++) {
      #pragma unroll
      for (int i = 0; i < 8; i++) {
        int e = c8*8 + i;
        float4 w0 = ew4[e*2], w1 = ew4[e*2+1];
        float eo = eb[e]
          + t8v[0]*w0.x + t8v[1]*w0.y + t8v[2]*w0.z + t8v[3]*w0.w
          + t8v[4]*w1.x + t8v[5]*w1.y + t8v[6]*w1.z + t8v[7]*w1.w;
        eo_s[i][y] = eo;
        out_edge[((size_t)(b*64 + e)*256 + x0 + r)*256 + y] = eo;
      }
      __syncthreads();
      #pragma unroll
      for (int k2 = 0; k2 < 2; k2++) {
        int ii = wv*2 + k2;
        int e = c8*8 + ii;
        float4 vv = *(const float4*)&eo_s[ii][lane*4];
        float4 mm = *(const float4*)&mk[r][lane*4];
        float b0 = vv.x+mm.x, b1 = vv.y+mm.y, b2 = vv.z+mm.z, b3 = vv.w+mm.w;
        float mx = fmaxf(fmaxf(b0, b1), fmaxf(b2, b3));
        #pragma unroll
        for (int off = 32; off; off >>= 1) mx = fmaxf(mx, __shfl_xor(mx, off, 64));
        float e0 = __expf(b0-mx), e1 = __expf(b1-mx), e2 = __expf(b2-mx), e3 = __expf(b3-mx);
        float se  = e0 + e1 + e2 + e3;
        float swe = e0*vv.x + e1*vv.y + e2*vv.z + e3*vv.w;  // weights*UNMASKED eo
        #pragma unroll
        for (int off = 32; off; off >>= 1) { se += __shfl_xor(se, off, 64); swe += __shfl_xor(swe, off, 64); }
        if (lane == 0) pl2[r][e] = swe / se;
      }
      __syncthreads();
    }
  }

  // ---- phase 6: node_tmp = PV + pool @ fc_w^T + fc_b  (bf16 out)
  const float4* fw4 = (const float4*)fcw;
  #pragma unroll
  for (int pass = 0; pass < 2; pass++) {
    int cdx = t + pass*256;
    float bias_c = fcb[cdx];
    float a0 = nacc[pass][0] + bias_c;
    float a1 = nacc[pass][1] + bias_c;
    #pragma unroll 4
    for (int e4 = 0; e4 < 16; e4++) {
      float4 f = fw4[(size_t)cdx*16 + e4];
      a0 += pl2[0][e4*4+0]*f.x + pl2[0][e4*4+1]*f.y + pl2[0][e4*4+2]*f.z + pl2[0][e4*4+3]*f.w;
      a1 += pl2[1][e4*4+0]*f.x + pl2[1][e4*4+1]*f.y + pl2[1][e4*4+2]*f.z + pl2[1][e4*4+3]*f.w;
    }
    union { __hip_bfloat16 h; unsigned short s; } u0, u1;
    u0.h = __float2bfloat16(a0);
    u1.h = __float2bfloat16(a1);
    tmpb[((size_t)b*256 + x0    )*512 + cdx] = u0.s;
    tmpb[((size_t)b*256 + x0 + 1)*512 + cdx] = u1.s;
  }
}

// ---------------- Kernel 3: output projection GEMM + bias (bf16 in) ---------
__global__ __launch_bounds__(256) void proj_gemm(
    const unsigned short* __restrict__ Xb, const float* __restrict__ W,
    const float* __restrict__ bias, float* __restrict__ out)
{
  __shared__ alignas(16) float A_s[16][136];
  __shared__ alignas(16) float W_s[16][72];
  const int t  = threadIdx.x;
  const int m0 = blockIdx.x * 128;
  const int o0 = blockIdx.y * 64;
  const int tm = (t & 15) * 8;
  const int to = (t >> 4) * 4;
  float acc[8][4];
  #pragma unroll
  for (int i = 0; i < 8; i++)
    #pragma unroll
    for (int j = 0; j < 4; j++) acc[i][j] = 0.f;

  const uint4* X4 = (const uint4*)Xb;   // row = 64 uint4 (512 bf16)
  const float4* W4 = (const float4*)W;
  for (int c0 = 0; c0 < 512; c0 += 16) {
    {
      int row = t >> 1, half = t & 1;   // 128 rows x 2 halves of 8 cols
      uint4 a = X4[(size_t)(m0 + row) * 64 + (c0 >> 3) + half];
      int cb = half*8;
      A_s[cb+0][row] = blo(a.x); A_s[cb+1][row] = bhi(a.x);
      A_s[cb+2][row] = blo(a.y); A_s[cb+3][row] = bhi(a.y);
      A_s[cb+4][row] = blo(a.z); A_s[cb+5][row] = bhi(a.z);
      A_s[cb+6][row] = blo(a.w); A_s[cb+7][row] = bhi(a.w);
    }
    {
      int row = t >> 2, quad = t & 3;
      float4 w = W4[(size_t)(o0 + row) * 128 + (c0 >> 2) + quad];
      W_s[quad*4+0][row] = w.x; W_s[quad*4+1][row] = w.y;
      W_s[quad*4+2][row] = w.z; W_s[quad*4+3][row] = w.w;
    }
    __syncthreads();
    #pragma unroll
    for (int kk = 0; kk < 16; kk++) {
      float4 a0 = *(const float4*)&A_s[kk][tm];
      float4 a1 = *(const float4*)&A_s[kk][tm + 4];
      float4 w0 = *(const float4*)&W_s[kk][to];
      float am[8] = {a0.x,a0.y,a0.z,a0.w,a1.x,a1.y,a1.z,a1.w};
      float wn[4] = {w0.x,w0.y,w0.z,w0.w};
      #pragma unroll
      for (int i = 0; i < 8; i++)
        #pragma unroll
        for (int j = 0; j < 4; j++) acc[i][j] += am[i] * wn[j];
    }
    __syncthreads();
  }
  float4 bb = *(const float4*)&bias[o0 + to];
  #pragma unroll
  for (int i = 0; i < 8; i++) {
    int m = m0 + tm + i;
    float4 r = make_float4(acc[i][0]+bb.x, acc[i][1]+bb.y, acc[i][2]+bb.z, acc[i][3]+bb.w);
    *(float4*)&out[(size_t)m*512 + o0 + to] = r;
  }
}

extern "C" void kernel_launch(void* const* d_in, const int* in_sizes, int n_in,
                              void* d_out, int out_size, void* d_ws, size_t ws_size,
                              hipStream_t stream)
{
  (void)in_sizes; (void)n_in; (void)out_size; (void)ws_size;
  const float* node   = (const float*)d_in[0];
  const float* edge   = (const float*)d_in[1];
  const unsigned char* mask = (const unsigned char*)d_in[2];
  const float* qkv_w  = (const float*)d_in[3];
  const float* proj_w = (const float*)d_in[4];
  const float* proj_b = (const float*)d_in[5];
  const float* rw     = (const float*)d_in[6];
  const float* rb     = (const float*)d_in[7];
  const float* ew     = (const float*)d_in[8];
  const float* eb     = (const float*)d_in[9];
  const float* fcw    = (const float*)d_in[10];
  const float* fcb    = (const float*)d_in[11];

  float* out_node = (float*)d_out;
  float* out_edge = out_node + (size_t)16*256*512;     // 2,097,152 floats

  // workspace: 16 MB total (bf16 intermediates)
  char* ws = (char*)d_ws;
  unsigned short* qb  = (unsigned short*)(ws);                    // 4 MB
  unsigned*       ktp = (unsigned*)      (ws + 4u*1024*1024);     // 4 MB
  unsigned*       vpp = (unsigned*)      (ws + 8u*1024*1024);     // 4 MB
  unsigned short* tmpb= (unsigned short*)(ws + 12u*1024*1024);    // 4 MB

  qkv_gemm <<<dim3(32, 24, 1), 256, 0, stream>>>(node, qkv_w, qb, ktp, vpp);
  fused_attn<<<dim3(2048, 1, 1), 256, 0, stream>>>(qb, ktp, vpp, edge, mask,
                                                   rw, rb, ew, eb, fcw, fcb,
                                                   out_edge, tmpb);
  proj_gemm<<<dim3(32, 8, 1), 256, 0, stream>>>(tmpb, proj_w, proj_b, out_node);
}

// Round 4
// 383.444 us; speedup vs baseline: 1.0716x; 1.0716x over previous
//
#include <hip/hip_runtime.h>
#include <hip/hip_bf16.h>
#include <cstdint>
#include <cstddef>

#define SCALE_ 0.125f
// B=16 N=256 C=512 H=8 HD=64 E=64

__device__ __forceinline__ unsigned pk2(float a, float b) {
  union { __hip_bfloat16 h[2]; unsigned u; } x;
  x.h[0] = __float2bfloat16(a);
  x.h[1] = __float2bfloat16(b);
  return x.u;
}
__device__ __forceinline__ unsigned short bf16b(float a) {
  union { __hip_bfloat16 h; unsigned short s; } x;
  x.h = __float2bfloat16(a);
  return x.s;
}
__device__ __forceinline__ float blo(unsigned u) { return __uint_as_float(u << 16); }
__device__ __forceinline__ float bhi(unsigned u) { return __uint_as_float(u & 0xffff0000u); }

// ---------------- Kernel 1: QKV projection GEMM (f32 in, bf16 out) ----------
// X[4096][512] ; W[1536][512] (row-major, y = x @ W^T)
// qb : bf16  [BH][N][64]
// ktq: uint2 [BH][16][256]  entry (d4,y) = {pk2(k[4d4],k[4d4+1]), pk2(k[4d4+2],k[4d4+3])}
// vq : uint2 [BH][64][64]   entry (y4,d) = {pk2(v[4y4][d],v[4y4+1][d]), pk2(v[4y4+2][d],v[4y4+3][d])}
__global__ __launch_bounds__(256) void qkv_gemm(
    const float* __restrict__ X, const float* __restrict__ W,
    unsigned short* __restrict__ qb, uint2* __restrict__ ktq, uint2* __restrict__ vq)
{
  __shared__ alignas(16) float A_s[16][136];
  __shared__ alignas(16) float W_s[16][72];
  const int t  = threadIdx.x;
  const int m0 = blockIdx.x * 128;
  const int o0 = blockIdx.y * 64;
  const int tm = (t & 15) * 8;
  const int to = (t >> 4) * 4;
  float acc[8][4];
  #pragma unroll
  for (int i = 0; i < 8; i++)
    #pragma unroll
    for (int j = 0; j < 4; j++) acc[i][j] = 0.f;

  const float4* X4 = (const float4*)X;
  const float4* W4 = (const float4*)W;
  for (int c0 = 0; c0 < 512; c0 += 16) {
    #pragma unroll
    for (int i = 0; i < 2; i++) {
      int id = t + 256 * i;
      int row = id >> 2, quad = id & 3;
      float4 a = X4[(size_t)(m0 + row) * 128 + (c0 >> 2) + quad];
      A_s[quad*4+0][row] = a.x; A_s[quad*4+1][row] = a.y;
      A_s[quad*4+2][row] = a.z; A_s[quad*4+3][row] = a.w;
    }
    {
      int row = t >> 2, quad = t & 3;
      float4 w = W4[(size_t)(o0 + row) * 128 + (c0 >> 2) + quad];
      W_s[quad*4+0][row] = w.x; W_s[quad*4+1][row] = w.y;
      W_s[quad*4+2][row] = w.z; W_s[quad*4+3][row] = w.w;
    }
    __syncthreads();
    #pragma unroll
    for (int kk = 0; kk < 16; kk++) {
      float4 a0 = *(const float4*)&A_s[kk][tm];
      float4 a1 = *(const float4*)&A_s[kk][tm + 4];
      float4 w0 = *(const float4*)&W_s[kk][to];
      float am[8] = {a0.x,a0.y,a0.z,a0.w,a1.x,a1.y,a1.z,a1.w};
      float wn[4] = {w0.x,w0.y,w0.z,w0.w};
      #pragma unroll
      for (int i = 0; i < 8; i++)
        #pragma unroll
        for (int j = 0; j < 4; j++) acc[i][j] += am[i] * wn[j];
    }
    __syncthreads();
  }
  // scatter store (bf16): this block's o-range is one (three,h) group
  const int three = o0 >> 9;
  const int h = (o0 >> 6) & 7;
  if (three == 0) {
    #pragma unroll
    for (int i = 0; i < 8; i++) {
      int m = m0 + tm + i;
      int b = m >> 8, n = m & 255;
      unsigned u0 = pk2(acc[i][0], acc[i][1]);
      unsigned u1 = pk2(acc[i][2], acc[i][3]);
      *(uint2*)&qb[((size_t)(b*8 + h)*256 + n)*64 + to] = make_uint2(u0, u1);
    }
  } else if (three == 1) {
    #pragma unroll
    for (int i = 0; i < 8; i++) {
      int m = m0 + tm + i;
      int b = m >> 8, n = m & 255;
      ktq[(size_t)(b*8 + h)*4096 + (size_t)(to >> 2)*256 + n] =
        make_uint2(pk2(acc[i][0], acc[i][1]), pk2(acc[i][2], acc[i][3]));
    }
  } else {
    int m = m0 + tm;                 // multiple of 8 -> same b for 8 rows
    int b = m >> 8, n0 = m & 255;
    #pragma unroll
    for (int ii = 0; ii < 2; ii++) {
      #pragma unroll
      for (int j = 0; j < 4; j++) {
        vq[(size_t)(b*8 + h)*4096 + (size_t)((n0 >> 2) + ii)*64 + to + j] =
          make_uint2(pk2(acc[4*ii+0][j], acc[4*ii+1][j]),
                     pk2(acc[4*ii+2][j], acc[4*ii+3][j]));
      }
    }
  }
}

// ---------------- Kernel 2: fused attn + edge pipeline ----------------------
// one block per (b, pair of query rows x0,x0+1); 256 threads = 4 waves.
// Scores live in registers: thread t owns column y=t for all 16 (r,h) rows.
__global__ __launch_bounds__(256, 4) void fused_attn(
    const unsigned short* __restrict__ qb, const uint2* __restrict__ ktq,
    const uint2* __restrict__ vq,
    const float* __restrict__ edge, const unsigned char* __restrict__ mask,
    const float* __restrict__ rw, const float* __restrict__ rb,
    const float* __restrict__ ew, const float* __restrict__ eb,
    const float* __restrict__ fcw, const float* __restrict__ fcb,
    float* __restrict__ out_edge, unsigned short* __restrict__ tmpb)
{
  __shared__ alignas(16) float q_s[2][8][64];
  __shared__ alignas(16) float rw_s[64][8];            // [e][h]
  __shared__ alignas(16) float ew_s[64][8];            // [e][h]
  __shared__ alignas(16) float eb_s[64];
  __shared__ alignas(16) float mk_s[2][256];           // additive mask
  __shared__ alignas(16) unsigned short p_sb[2][8][256]; // exp scores, bf16
  __shared__ alignas(16) float eo_s[16][256];
  __shared__ float redm[16][4];
  __shared__ float redsum[16][4];
  __shared__ float pl2[2][64];

  const int t = threadIdx.x;
  const int lane = t & 63;
  const int wv = t >> 6;
  const int bid = blockIdx.x;
  const int b = bid >> 7;
  const int x0 = (bid & 127) * 2;
  const int y = t;

  // ---- phase 1: stage q (bf16->f32), small weights, mask
  {
    int r = t >> 7, h = (t >> 4) & 7, d0 = (t & 15) * 4;
    uint2 u = *(const uint2*)&qb[((size_t)(b*8 + h)*256 + x0 + r)*64 + d0];
    q_s[r][h][d0+0] = blo(u.x); q_s[r][h][d0+1] = bhi(u.x);
    q_s[r][h][d0+2] = blo(u.y); q_s[r][h][d0+3] = bhi(u.y);
  }
  for (int i = t; i < 512; i += 256) { int e = i >> 3, h = i & 7; rw_s[e][h] = rw[h*64 + e]; }
  for (int i = t; i < 512; i += 256) ((float*)ew_s)[i] = ew[i];
  if (t < 64) eb_s[t] = eb[t];
  const float mk0 = mask[(size_t)b*65536 + (size_t)x0*256 + y]       ? -1e30f : 0.f;
  const float mk1 = mask[(size_t)b*65536 + (size_t)(x0 + 1)*256 + y] ? -1e30f : 0.f;
  mk_s[0][y] = mk0; mk_s[1][y] = mk1;
  __syncthreads();

  // ---- phase 2a: edge bias (268 MB HBM stream, coalesced over y)
  // per-b slab of edge is E*N*N = 64*65536 floats (round-3 bug: was b*16777216)
  float accv[16];   // i = r*8 + h
  #pragma unroll
  for (int h = 0; h < 8; h++) { float rv = rb[h]; accv[h] = rv; accv[8+h] = rv; }
  {
    const float* ep = edge + (size_t)b*(64*65536) + (size_t)x0*256 + y;
    #pragma unroll 8
    for (int e = 0; e < 64; e++) {
      float v0 = ep[(size_t)e*65536];
      float v1 = ep[(size_t)e*65536 + 256];
      #pragma unroll
      for (int h = 0; h < 8; h++) {
        float w = rw_s[e][h];
        accv[h]   += v0 * w;
        accv[8+h] += v1 * w;
      }
    }
  }

  // ---- phase 2b: QK^T (ktq: uint2 of 4 d's per load, coalesced over y)
  #pragma unroll
  for (int h = 0; h < 8; h++) {
    const uint2* kq = ktq + (size_t)(b*8 + h)*4096 + y;
    const float4* qa4 = (const float4*)q_s[0][h];
    const float4* qc4 = (const float4*)q_s[1][h];
    float qk0 = 0.f, qk1 = 0.f;
    #pragma unroll
    for (int d4 = 0; d4 < 16; d4++) {
      uint2 u = kq[(size_t)d4*256];
      float k0 = blo(u.x), k1 = bhi(u.x), k2 = blo(u.y), k3 = bhi(u.y);
      float4 qa = qa4[d4], qc = qc4[d4];
      qk0 += qa.x*k0 + qa.y*k1 + qa.z*k2 + qa.w*k3;
      qk1 += qc.x*k0 + qc.y*k1 + qc.z*k2 + qc.w*k3;
    }
    accv[h]   += SCALE_ * qk0;
    accv[8+h] += SCALE_ * qk1;
  }

  // ---- phase 3: softmax (wave shfl reduce + tiny cross-wave LDS combine)
  float p[16];
  #pragma unroll
  for (int i = 0; i < 16; i++) p[i] = accv[i] + (i < 8 ? mk0 : mk1);
  {
    float wred[16];
    #pragma unroll
    for (int i = 0; i < 16; i++) {
      float v = p[i];
      #pragma unroll
      for (int off = 32; off; off >>= 1) v = fmaxf(v, __shfl_xor(v, off, 64));
      wred[i] = v;
    }
    if (lane == 0) {
      #pragma unroll
      for (int i = 0; i < 16; i++) redm[i][wv] = wred[i];
    }
    __syncthreads();
    #pragma unroll
    for (int i = 0; i < 16; i++) {
      float mx = fmaxf(fmaxf(redm[i][0], redm[i][1]), fmaxf(redm[i][2], redm[i][3]));
      p[i] = __expf(p[i] - mx);
    }
    #pragma unroll
    for (int i = 0; i < 16; i++) {
      float v = p[i];
      #pragma unroll
      for (int off = 32; off; off >>= 1) v += __shfl_xor(v, off, 64);
      wred[i] = v;
    }
    if (lane == 0) {
      #pragma unroll
      for (int i = 0; i < 16; i++) redsum[i][wv] = wred[i];
    }
    #pragma unroll
    for (int i = 0; i < 16; i++) p_sb[i>>3][i&7][y] = bf16b(p[i]);
    __syncthreads();
  }

  // ---- phase 4: PV. wave wv does heads wv and wv+4 (d = lane)
  float nacc[2][2]; // [pass][r]
  #pragma unroll
  for (int pass = 0; pass < 2; pass++) {
    int h = wv + pass*4;
    float s0 = redsum[h][0]   + redsum[h][1]   + redsum[h][2]   + redsum[h][3];
    float s1 = redsum[8+h][0] + redsum[8+h][1] + redsum[8+h][2] + redsum[8+h][3];
    const uint2* vp = vq + (size_t)(b*8 + h)*4096 + lane;
    const uint2* pa = (const uint2*)&p_sb[0][h][0];
    const uint2* pb = (const uint2*)&p_sb[1][h][0];
    float a0 = 0.f, a1 = 0.f;
    #pragma unroll 8
    for (int y4 = 0; y4 < 64; y4++) {
      uint2 uv = vp[(size_t)y4*64];
      uint2 P0 = pa[y4];
      uint2 P1 = pb[y4];
      float v0 = blo(uv.x), v1 = bhi(uv.x), v2 = blo(uv.y), v3 = bhi(uv.y);
      a0 += blo(P0.x)*v0 + bhi(P0.x)*v1 + blo(P0.y)*v2 + bhi(P0.y)*v3;
      a1 += blo(P1.x)*v0 + bhi(P1.x)*v1 + blo(P1.y)*v2 + bhi(P1.y)*v3;
    }
    nacc[pass][0] = a0 / s0;
    nacc[pass][1] = a1 / s1;
  }

  float invreg[16];
  #pragma unroll
  for (int i = 0; i < 16; i++)
    invreg[i] = 1.f / (redsum[i][0] + redsum[i][1] + redsum[i][2] + redsum[i][3]);

  // ---- phase 5: expand + edge_out write + row pooling (chunks of 16 e)
  const float4* ew4 = (const float4*)ew_s;
  for (int r = 0; r < 2; r++) {
    float t8v[8];
    #pragma unroll
    for (int h = 0; h < 8; h++) {
      int i = r*8 + h;
      t8v[h] = p[i]*invreg[i] + accv[i];  // attn_sm + residual
    }
    for (int c16 = 0; c16 < 4; c16++) {
      #pragma unroll
      for (int i = 0; i < 16; i++) {
        int e = c16*16 + i;
        float4 w0 = ew4[e*2], w1 = ew4[e*2+1];
        float eo = eb_s[e]
          + t8v[0]*w0.x + t8v[1]*w0.y + t8v[2]*w0.z + t8v[3]*w0.w
          + t8v[4]*w1.x + t8v[5]*w1.y + t8v[6]*w1.z + t8v[7]*w1.w;
        eo_s[i][y] = eo;
        __builtin_nontemporal_store(eo, &out_edge[((size_t)(b*64 + e)*256 + x0 + r)*256 + y]);
      }
      __syncthreads();
      #pragma unroll
      for (int k2 = 0; k2 < 4; k2++) {
        int ii = wv*4 + k2;
        int e = c16*16 + ii;
        float4 vv = *(const float4*)&eo_s[ii][lane*4];
        float4 mm = *(const float4*)&mk_s[r][lane*4];
        float b0 = vv.x+mm.x, b1 = vv.y+mm.y, b2 = vv.z+mm.z, b3 = vv.w+mm.w;
        float mx = fmaxf(fmaxf(b0, b1), fmaxf(b2, b3));
        #pragma unroll
        for (int off = 32; off; off >>= 1) mx = fmaxf(mx, __shfl_xor(mx, off, 64));
        float e0 = __expf(b0-mx), e1 = __expf(b1-mx), e2 = __expf(b2-mx), e3 = __expf(b3-mx);
        float se  = e0 + e1 + e2 + e3;
        float swe = e0*vv.x + e1*vv.y + e2*vv.z + e3*vv.w;  // weights * UNMASKED eo
        #pragma unroll
        for (int off = 32; off; off >>= 1) { se += __shfl_xor(se, off, 64); swe += __shfl_xor(swe, off, 64); }
        if (lane == 0) pl2[r][e] = swe / se;
      }
      __syncthreads();
    }
  }

  // ---- phase 6: node_tmp = PV + pool @ fc_w^T + fc_b  (bf16 out)
  const float4* fw4 = (const float4*)fcw;
  #pragma unroll
  for (int pass = 0; pass < 2; pass++) {
    int cdx = t + pass*256;
    float bias_c = fcb[cdx];
    float a0 = nacc[pass][0] + bias_c;
    float a1 = nacc[pass][1] + bias_c;
    #pragma unroll 4
    for (int e4 = 0; e4 < 16; e4++) {
      float4 f = fw4[(size_t)cdx*16 + e4];
      a0 += pl2[0][e4*4+0]*f.x + pl2[0][e4*4+1]*f.y + pl2[0][e4*4+2]*f.z + pl2[0][e4*4+3]*f.w;
      a1 += pl2[1][e4*4+0]*f.x + pl2[1][e4*4+1]*f.y + pl2[1][e4*4+2]*f.z + pl2[1][e4*4+3]*f.w;
    }
    tmpb[((size_t)b*256 + x0    )*512 + cdx] = bf16b(a0);
    tmpb[((size_t)b*256 + x0 + 1)*512 + cdx] = bf16b(a1);
  }
}

// ---------------- Kernel 3: output projection GEMM + bias (bf16 in) ---------
__global__ __launch_bounds__(256) void proj_gemm(
    const unsigned short* __restrict__ Xb, const float* __restrict__ W,
    const float* __restrict__ bias, float* __restrict__ out)
{
  __shared__ alignas(16) float A_s[16][136];
  __shared__ alignas(16) float W_s[16][72];
  const int t  = threadIdx.x;
  const int m0 = blockIdx.x * 128;
  const int o0 = blockIdx.y * 64;
  const int tm = (t & 15) * 8;
  const int to = (t >> 4) * 4;
  float acc[8][4];
  #pragma unroll
  for (int i = 0; i < 8; i++)
    #pragma unroll
    for (int j = 0; j < 4; j++) acc[i][j] = 0.f;

  const uint4* X4 = (const uint4*)Xb;   // row = 64 uint4 (512 bf16)
  const float4* W4 = (const float4*)W;
  for (int c0 = 0; c0 < 512; c0 += 16) {
    {
      int row = t >> 1, half = t & 1;   // 128 rows x 2 halves of 8 cols
      uint4 a = X4[(size_t)(m0 + row) * 64 + (c0 >> 3) + half];
      int cb = half*8;
      A_s[cb+0][row] = blo(a.x); A_s[cb+1][row] = bhi(a.x);
      A_s[cb+2][row] = blo(a.y); A_s[cb+3][row] = bhi(a.y);
      A_s[cb+4][row] = blo(a.z); A_s[cb+5][row] = bhi(a.z);
      A_s[cb+6][row] = blo(a.w); A_s[cb+7][row] = bhi(a.w);
    }
    {
      int row = t >> 2, quad = t & 3;
      float4 w = W4[(size_t)(o0 + row) * 128 + (c0 >> 2) + quad];
      W_s[quad*4+0][row] = w.x; W_s[quad*4+1][row] = w.y;
      W_s[quad*4+2][row] = w.z; W_s[quad*4+3][row] = w.w;
    }
    __syncthreads();
    #pragma unroll
    for (int kk = 0; kk < 16; kk++) {
      float4 a0 = *(const float4*)&A_s[kk][tm];
      float4 a1 = *(const float4*)&A_s[kk][tm + 4];
      float4 w0 = *(const float4*)&W_s[kk][to];
      float am[8] = {a0.x,a0.y,a0.z,a0.w,a1.x,a1.y,a1.z,a1.w};
      float wn[4] = {w0.x,w0.y,w0.z,w0.w};
      #pragma unroll
      for (int i = 0; i < 8; i++)
        #pragma unroll
        for (int j = 0; j < 4; j++) acc[i][j] += am[i] * wn[j];
    }
    __syncthreads();
  }
  float4 bb = *(const float4*)&bias[o0 + to];
  #pragma unroll
  for (int i = 0; i < 8; i++) {
    int m = m0 + tm + i;
    float4 r = make_float4(acc[i][0]+bb.x, acc[i][1]+bb.y, acc[i][2]+bb.z, acc[i][3]+bb.w);
    *(float4*)&out[(size_t)m*512 + o0 + to] = r;
  }
}

extern "C" void kernel_launch(void* const* d_in, const int* in_sizes, int n_in,
                              void* d_out, int out_size, void* d_ws, size_t ws_size,
                              hipStream_t stream)
{
  (void)in_sizes; (void)n_in; (void)out_size; (void)ws_size;
  const float* node   = (const float*)d_in[0];
  const float* edge   = (const float*)d_in[1];
  const unsigned char* mask = (const unsigned char*)d_in[2];
  const float* qkv_w  = (const float*)d_in[3];
  const float* proj_w = (const float*)d_in[4];
  const float* proj_b = (const float*)d_in[5];
  const float* rw     = (const float*)d_in[6];
  const float* rb     = (const float*)d_in[7];
  const float* ew     = (const float*)d_in[8];
  const float* eb     = (const float*)d_in[9];
  const float* fcw    = (const float*)d_in[10];
  const float* fcb    = (const float*)d_in[11];

  float* out_node = (float*)d_out;
  float* out_edge = out_node + (size_t)16*256*512;     // 2,097,152 floats

  // workspace: 16 MB total (bf16 intermediates)
  char* ws = (char*)d_ws;
  unsigned short* qb  = (unsigned short*)(ws);                    // 4 MB
  uint2*          ktq = (uint2*)         (ws + 4u*1024*1024);     // 4 MB
  uint2*          vq  = (uint2*)         (ws + 8u*1024*1024);     // 4 MB
  unsigned short* tmpb= (unsigned short*)(ws + 12u*1024*1024);    // 4 MB

  qkv_gemm <<<dim3(32, 24, 1), 256, 0, stream>>>(node, qkv_w, qb, ktq, vq);
  fused_attn<<<dim3(2048, 1, 1), 256, 0, stream>>>(qb, ktq, vq, edge, mask,
                                                   rw, rb, ew, eb, fcw, fcb,
                                                   out_edge, tmpb);
  proj_gemm<<<dim3(32, 8, 1), 256, 0, stream>>>(tmpb, proj_w, proj_b, out_node);
}